// Round 12
// baseline (127.636 us; speedup 1.0000x reference)
//
#include <hip/hip_runtime.h>

#define NN 40000
#define NE 640000
#define D 128
#define CAP 64  // bucket capacity; P(Poisson(16) >= 64) ~ 3e-22

typedef __attribute__((ext_vector_type(8))) short short8;
typedef __attribute__((ext_vector_type(4))) float f32x4;
typedef __attribute__((ext_vector_type(4))) int i32x4;

__device__ __forceinline__ short f2b(float v) {
  unsigned int u = __builtin_bit_cast(unsigned int, v);
  u = (u + 0x7fffu + ((u >> 16) & 1u)) >> 16;
  return (short)u;
}
__device__ __forceinline__ float b2f(short s) {
  unsigned int u = ((unsigned int)(unsigned short)s) << 16;
  return __builtin_bit_cast(float, u);
}

// ---------------- K0: weights (bf16 transpose + Wg hi/lo split), zero cnt,
// zero dummy hg-row (index NN), bsum = bn + bg ------------------------------
__global__ __launch_bounds__(256) void k_prep(
    const float* __restrict__ Wn, const float* __restrict__ Wg,
    const float* __restrict__ Wa, const float* __restrict__ bn,
    const float* __restrict__ bg, short* __restrict__ WnT,
    short* __restrict__ WgThi, short* __restrict__ WgTlo,
    short* __restrict__ WaT, int* __restrict__ cnt, float* __restrict__ hg,
    float* __restrict__ bsum) {
  int i = blockIdx.x * 256 + threadIdx.x;  // 0..16383
  int k = i >> 7, c = i & 127;
  WnT[c * D + k] = f2b(Wn[k * D + c]);
  WaT[c * D + k] = f2b(Wa[k * D + c]);
  float v = Wg[k * D + c];
  short hi = f2b(v);
  WgThi[c * D + k] = hi;
  WgTlo[c * D + k] = f2b(v - b2f(hi));
  if (i < 10000) {  // zero cnt: 40000 ints = 10000 int4
    i32x4 z = {0, 0, 0, 0};
    *(i32x4*)(cnt + i * 4) = z;
  }
  if (i < 32) {  // zero dummy row hg[NN]
    f32x4 z = {0.f, 0.f, 0.f, 0.f};
    *(f32x4*)(hg + (size_t)NN * D + i * 4) = z;
  }
  if (i < 128) bsum[i] = bn[i] + bg[i];
}

// ---------------- K1: edge bucket fill (u16 cols) ----------------
__global__ __launch_bounds__(256) void k_fill(
    const int* __restrict__ ei, int* __restrict__ cnt,
    unsigned short* __restrict__ bucket) {
  int e = blockIdx.x * 256 + threadIdx.x;
  if (e >= NE) return;
  int r = ei[e];       // destination row
  int c = ei[NE + e];  // source col
  int slot = atomicAdd(&cnt[r], 1);
  if (slot < CAP) bucket[(size_t)r * CAP + slot] = (unsigned short)c;
}

// ---------------- K2: node transform (16 rows/block) ----------------------
// Computes alpha = sigmoid(x@Wa+ba) via MFMA, h = x*alpha (bf16, in-reg),
// then hg = h@Wg (hi+lo split on B only; h is bf16-exact) and xn = x@Wn.
// xn -> d_out (staging), hg -> hg buffer. h never hits global memory.
// A-frag: lane l holds row (l&15), k = kt*32 + (l>>4)*8 + j
// B-frag: lane l holds col (l&15), same k slots -> permutation-safe.
// C/D: col = lane&15, row = (lane>>4)*4 + reg
__global__ __launch_bounds__(256) void k_node(
    const float* __restrict__ x, const short* __restrict__ WaT,
    const short* __restrict__ WnT, const short* __restrict__ WgThi,
    const short* __restrict__ WgTlo, const float* __restrict__ ba,
    float* __restrict__ hg, float* __restrict__ xn_out) {
  __shared__ float xs[16][132];    // x tile (staged coalesced)
  __shared__ float al_s[16][132];  // alpha tile
  int r0 = blockIdx.x * 16;
  int t = threadIdx.x;
  int w = t >> 6, l = t & 63;
  int g = l >> 4, c16 = l & 15;

#pragma unroll
  for (int p = 0; p < 2; ++p) {
    int idx = t + p * 256;  // 0..511
    int row = idx >> 5, cv = idx & 31;
    f32x4 v = *(const f32x4*)(x + (size_t)(r0 + row) * D + cv * 4);
    *(f32x4*)&xs[row][cv * 4] = v;
  }
  __syncthreads();

  short8 a[4];
#pragma unroll
  for (int kt = 0; kt < 4; ++kt) {
    f32x4 v0 = *(const f32x4*)&xs[c16][kt * 32 + g * 8];
    f32x4 v1 = *(const f32x4*)&xs[c16][kt * 32 + g * 8 + 4];
    short8 tt;
    tt[0] = f2b(v0[0]); tt[1] = f2b(v0[1]); tt[2] = f2b(v0[2]); tt[3] = f2b(v0[3]);
    tt[4] = f2b(v1[0]); tt[5] = f2b(v1[1]); tt[6] = f2b(v1[2]); tt[7] = f2b(v1[3]);
    a[kt] = tt;
  }

  // alpha GEMM
#pragma unroll
  for (int u = 0; u < 2; ++u) {
    int ct = w * 2 + u;
    int cc = ct * 16 + c16;
    f32x4 c = {0.f, 0.f, 0.f, 0.f};
#pragma unroll
    for (int kt = 0; kt < 4; ++kt) {
      short8 b = *(const short8*)(WaT + (size_t)cc * D + kt * 32 + g * 8);
      c = __builtin_amdgcn_mfma_f32_16x16x32_bf16(a[kt], b, c, 0, 0, 0);
    }
    float bav = ba[cc];
#pragma unroll
    for (int r = 0; r < 4; ++r) {
      float tv = c[r] + bav;
      al_s[g * 4 + r][cc] = 1.0f / (1.0f + __expf(-tv));
    }
  }
  __syncthreads();

  // h A-frags in-register: h = bf16(x_f32 * alpha), same (lane,k) map as a[]
  short8 ha[4];
#pragma unroll
  for (int kt = 0; kt < 4; ++kt) {
    short8 tt;
#pragma unroll
    for (int q = 0; q < 8; ++q) {
      int ch = kt * 32 + g * 8 + q;
      tt[q] = f2b(xs[c16][ch] * al_s[c16][ch]);
    }
    ha[kt] = tt;
  }

  // xn = x@Wn -> d_out staging; hg = h@Wg (2 MFMA per tile: B hi + B lo)
#pragma unroll
  for (int u = 0; u < 2; ++u) {
    int ct = w * 2 + u;
    int cc = ct * 16 + c16;
    f32x4 cn = {0.f, 0.f, 0.f, 0.f};
    f32x4 cg = {0.f, 0.f, 0.f, 0.f};
#pragma unroll
    for (int kt = 0; kt < 4; ++kt) {
      short8 bwn = *(const short8*)(WnT + (size_t)cc * D + kt * 32 + g * 8);
      short8 bh = *(const short8*)(WgThi + (size_t)cc * D + kt * 32 + g * 8);
      short8 bl = *(const short8*)(WgTlo + (size_t)cc * D + kt * 32 + g * 8);
      cn = __builtin_amdgcn_mfma_f32_16x16x32_bf16(a[kt], bwn, cn, 0, 0, 0);
      cg = __builtin_amdgcn_mfma_f32_16x16x32_bf16(ha[kt], bh, cg, 0, 0, 0);
      cg = __builtin_amdgcn_mfma_f32_16x16x32_bf16(ha[kt], bl, cg, 0, 0, 0);
    }
#pragma unroll
    for (int r = 0; r < 4; ++r) {
      int rr = r0 + g * 4 + r;
      xn_out[(size_t)rr * D + cc] = cn[r];
      hg[(size_t)rr * D + cc] = cg[r];
    }
  }
}

// 4 slots (S0+g, S0+4+g, S0+8+g, S0+12+g) -> 8 independent 16B gathers
// (f32 rows), register indices, branchless dummy-row clamp.
#define SSTEP(S0, CA, CB, CC, CD)                                   \
  {                                                                 \
    int q0 = (S0) + g < deg ? (CA) : NN;                            \
    int q1 = (S0) + 4 + g < deg ? (CB) : NN;                        \
    int q2 = (S0) + 8 + g < deg ? (CC) : NN;                        \
    int q3 = (S0) + 12 + g < deg ? (CD) : NN;                       \
    const float* p0 = hg + (size_t)q0 * D + i * 8;                  \
    const float* p1 = hg + (size_t)q1 * D + i * 8;                  \
    const float* p2 = hg + (size_t)q2 * D + i * 8;                  \
    const float* p3 = hg + (size_t)q3 * D + i * 8;                  \
    f32x4 v0a = *(const f32x4*)p0, v0b = *(const f32x4*)(p0 + 4);   \
    f32x4 v1a = *(const f32x4*)p1, v1b = *(const f32x4*)(p1 + 4);   \
    f32x4 v2a = *(const f32x4*)p2, v2b = *(const f32x4*)(p2 + 4);   \
    f32x4 v3a = *(const f32x4*)p3, v3b = *(const f32x4*)(p3 + 4);   \
    _Pragma("unroll") for (int q = 0; q < 4; ++q) {                 \
      acc[q] += v0a[q] + v1a[q] + v2a[q] + v3a[q];                  \
      acc[4 + q] += v0b[q] + v1b[q] + v2b[q] + v3b[q];              \
    }                                                               \
  }

// ---------------- K3: gather-sum hg + fused output epilogue ---------------
// 1 node/wave, no LDS, no barrier. Group g handles slots {g,4+g,8+g,12+g};
// chunk i=l&15 = channels [8i,8i+8). After shfl_xor reduce, g==0 lanes do
// out = tanh(xn + sum + bn + bg) in place (xn staged in d_out by k_node).
__global__ __launch_bounds__(256) void k_aggf(
    const int* __restrict__ cnt, const unsigned short* __restrict__ bucket,
    const float* __restrict__ hg, const float* __restrict__ bsum,
    float* __restrict__ out) {
  int l = threadIdx.x & 63;
  int n = blockIdx.x * 4 + (threadIdx.x >> 6);
  int g = l >> 4, i = l & 15;
  int deg = cnt[n];
  deg = deg < CAP ? deg : CAP;
  int bc = bucket[(size_t)n * CAP + l];
  float acc[8];
#pragma unroll
  for (int q = 0; q < 8; ++q) acc[q] = 0.f;

  int c0 = __shfl(bc, g), c1 = __shfl(bc, 4 + g);
  int c2 = __shfl(bc, 8 + g), c3 = __shfl(bc, 12 + g);
  SSTEP(0, c0, c1, c2, c3);
  if (deg > 16) {
    int c4 = __shfl(bc, 16 + g), c5 = __shfl(bc, 20 + g);
    int c6 = __shfl(bc, 24 + g), c7 = __shfl(bc, 28 + g);
    SSTEP(16, c4, c5, c6, c7);
  }
  if (deg > 32) {  // rare: P ~ 1.6e-4
    for (int j = 32; j < deg; j += 16) {
      int d0 = __shfl(bc, (j + g) & 63), d1 = __shfl(bc, (j + 4 + g) & 63);
      int d2 = __shfl(bc, (j + 8 + g) & 63), d3 = __shfl(bc, (j + 12 + g) & 63);
      SSTEP(j, d0, d1, d2, d3);
    }
  }

#pragma unroll
  for (int q = 0; q < 8; ++q) {
    acc[q] += __shfl_xor(acc[q], 16);
    acc[q] += __shfl_xor(acc[q], 32);
  }
  if (g == 0) {
    float* po = out + (size_t)n * D + i * 8;
    f32x4 x0 = *(const f32x4*)po;          // xn staged by k_node
    f32x4 x1 = *(const f32x4*)(po + 4);
    f32x4 b0 = *(const f32x4*)(bsum + i * 8);
    f32x4 b1 = *(const f32x4*)(bsum + i * 8 + 4);
    f32x4 o0, o1;
#pragma unroll
    for (int q = 0; q < 4; ++q) {
      o0[q] = tanhf(acc[q] + x0[q] + b0[q]);
      o1[q] = tanhf(acc[4 + q] + x1[q] + b1[q]);
    }
    *(f32x4*)po = o0;
    *(f32x4*)(po + 4) = o1;
  }
}

extern "C" void kernel_launch(void* const* d_in, const int* in_sizes, int n_in,
                              void* d_out, int out_size, void* d_ws,
                              size_t ws_size, hipStream_t stream) {
  const float* x = (const float*)d_in[0];
  const int* ei = (const int*)d_in[1];
  const float* Wn_w = (const float*)d_in[2];
  const float* Wn_b = (const float*)d_in[3];
  const float* Wg_w = (const float*)d_in[4];
  const float* Wg_b = (const float*)d_in[5];
  const float* Wa_w = (const float*)d_in[6];
  const float* Wa_b = (const float*)d_in[7];

  char* ws = (char*)d_ws;
  short* WaT = (short*)(ws + 0);
  short* WnT = (short*)(ws + 32 * 1024);
  short* WgThi = (short*)(ws + 64 * 1024);
  short* WgTlo = (short*)(ws + 96 * 1024);
  float* bsum = (float*)(ws + 128 * 1024);  // 512 B
  int* cnt = (int*)(ws + 132 * 1024);       // 160 KB
  size_t off = 512 * 1024;
  float* hg = (float*)(ws + off);  // (NN+1)*D*4 = 20.5 MB (+dummy row)
  off += (size_t)(NN + 1) * D * 4;
  unsigned short* bucket = (unsigned short*)(ws + off);  // 5.12 MB
  float* out = (float*)d_out;

  k_prep<<<64, 256, 0, stream>>>(Wn_w, Wg_w, Wa_w, Wn_b, Wg_b, WnT, WgThi,
                                 WgTlo, WaT, cnt, hg, bsum);
  k_fill<<<(NE + 255) / 256, 256, 0, stream>>>(ei, cnt, bucket);
  k_node<<<NN / 16, 256, 0, stream>>>(x, WaT, WnT, WgThi, WgTlo, Wa_b, hg,
                                      out);
  k_aggf<<<NN / 4, 256, 0, stream>>>(cnt, bucket, hg, bsum, out);
}

// Round 13
// 120.845 us; speedup vs baseline: 1.0562x; 1.0562x over previous
//
#include <hip/hip_runtime.h>

#define NN 40000
#define NE 640000
#define D 128
#define CAP 64  // bucket capacity; P(Poisson(16) >= 64) ~ 3e-22

typedef __attribute__((ext_vector_type(8))) short short8;
typedef __attribute__((ext_vector_type(4))) float f32x4;
typedef __attribute__((ext_vector_type(4))) int i32x4;

__device__ __forceinline__ short f2b(float v) {
  unsigned int u = __builtin_bit_cast(unsigned int, v);
  u = (u + 0x7fffu + ((u >> 16) & 1u)) >> 16;
  return (short)u;
}
__device__ __forceinline__ float b2f(short s) {
  unsigned int u = ((unsigned int)(unsigned short)s) << 16;
  return __builtin_bit_cast(float, u);
}

// ---------------- K0: weights (bf16 transpose + Wg hi/lo split), zero cnt,
// zero dummy h-row (index NN) used for branchless gather padding -----------
__global__ __launch_bounds__(256) void k_prep(
    const float* __restrict__ Wn, const float* __restrict__ Wg,
    const float* __restrict__ Wa, short* __restrict__ WnT,
    short* __restrict__ WgThi, short* __restrict__ WgTlo,
    short* __restrict__ WaT, int* __restrict__ cnt, short* __restrict__ h) {
  int i = blockIdx.x * 256 + threadIdx.x;  // 0..16383
  int k = i >> 7, c = i & 127;
  WnT[c * D + k] = f2b(Wn[k * D + c]);
  WaT[c * D + k] = f2b(Wa[k * D + c]);
  float v = Wg[k * D + c];
  short hi = f2b(v);
  WgThi[c * D + k] = hi;
  WgTlo[c * D + k] = f2b(v - b2f(hi));
  if (i < 10000) {  // zero cnt: 40000 ints = 10000 int4
    i32x4 z = {0, 0, 0, 0};
    *(i32x4*)(cnt + i * 4) = z;
  }
  if (i < 16) {  // zero dummy row h[NN]
    short8 z = {0, 0, 0, 0, 0, 0, 0, 0};
    *(short8*)(h + (size_t)NN * D + i * 8) = z;
  }
}

// ---------------- K1: edge bucket fill (u16 cols) ----------------
__global__ __launch_bounds__(256) void k_fill(
    const int* __restrict__ ei, int* __restrict__ cnt,
    unsigned short* __restrict__ bucket) {
  int e = blockIdx.x * 256 + threadIdx.x;
  if (e >= NE) return;
  int r = ei[e];       // destination row
  int c = ei[NE + e];  // source col
  int slot = atomicAdd(&cnt[r], 1);
  if (slot < CAP) bucket[(size_t)r * CAP + slot] = (unsigned short)c;
}

// ---------------- K2: node transform (16 rows/block, LDS-staged x) --------
// A-frag: lane l holds row (l&15), k = kt*32 + (l>>4)*8 + j
// B-frag: lane l holds col (l&15), same k slots -> permutation-safe.
// C/D: col = lane&15, row = (lane>>4)*4 + reg
__global__ __launch_bounds__(256) void k_node(
    const float* __restrict__ x, const short* __restrict__ WaT,
    const float* __restrict__ ba, short* __restrict__ h_out,
    short* __restrict__ xbf_out) {
  __shared__ float xs[16][132];    // x tile (staged coalesced)
  __shared__ float al_s[16][132];  // alpha tile
  int r0 = blockIdx.x * 16;
  int t = threadIdx.x;
  int w = t >> 6, l = t & 63;
  int g = l >> 4, c16 = l & 15;

#pragma unroll
  for (int p = 0; p < 2; ++p) {
    int idx = t + p * 256;  // 0..511
    int row = idx >> 5, cv = idx & 31;
    f32x4 v = *(const f32x4*)(x + (size_t)(r0 + row) * D + cv * 4);
    *(f32x4*)&xs[row][cv * 4] = v;
  }
  __syncthreads();

  short8 a[4];
#pragma unroll
  for (int kt = 0; kt < 4; ++kt) {
    f32x4 v0 = *(const f32x4*)&xs[c16][kt * 32 + g * 8];
    f32x4 v1 = *(const f32x4*)&xs[c16][kt * 32 + g * 8 + 4];
    short8 tt;
    tt[0] = f2b(v0[0]); tt[1] = f2b(v0[1]); tt[2] = f2b(v0[2]); tt[3] = f2b(v0[3]);
    tt[4] = f2b(v1[0]); tt[5] = f2b(v1[1]); tt[6] = f2b(v1[2]); tt[7] = f2b(v1[3]);
    a[kt] = tt;
    *(short8*)(xbf_out + (size_t)(r0 + c16) * D + kt * 32 + g * 8) = tt;
  }

#pragma unroll
  for (int u = 0; u < 2; ++u) {
    int ct = w * 2 + u;
    int cc = ct * 16 + c16;
    f32x4 c = {0.f, 0.f, 0.f, 0.f};
#pragma unroll
    for (int kt = 0; kt < 4; ++kt) {
      short8 b = *(const short8*)(WaT + (size_t)cc * D + kt * 32 + g * 8);
      c = __builtin_amdgcn_mfma_f32_16x16x32_bf16(a[kt], b, c, 0, 0, 0);
    }
    float bav = ba[cc];
#pragma unroll
    for (int r = 0; r < 4; ++r) {
      float tv = c[r] + bav;
      al_s[g * 4 + r][cc] = 1.0f / (1.0f + __expf(-tv));
    }
  }
  __syncthreads();

  // wave w handles channel chunk kt=w: h = x_f32 * alpha (bf16)
  short8 hh;
#pragma unroll
  for (int q = 0; q < 8; ++q) {
    float av = al_s[c16][w * 32 + g * 8 + q];
    float xv = xs[c16][w * 32 + g * 8 + q];
    hh[q] = f2b(xv * av);
  }
  *(short8*)(h_out + (size_t)(r0 + c16) * D + w * 32 + g * 8) = hh;
}

// one pair-step: slots 4*T0+g and 4*T0+4+g for both nodes; 4 independent
// 16B gathers, register indices, branchless dummy-row clamp.
#define PSTEP(T0, C0A, C0B, C1A, C1B)                               \
  {                                                                 \
    int s0 = 4 * (T0) + g, s1 = s0 + 4;                             \
    int ra0 = s0 < deg0 ? (C0A) : NN;                               \
    int ra1 = s1 < deg0 ? (C0B) : NN;                               \
    int rb0 = s0 < deg1 ? (C1A) : NN;                               \
    int rb1 = s1 < deg1 ? (C1B) : NN;                               \
    short8 va0 = *(const short8*)(h + (size_t)ra0 * D + i * 8);     \
    short8 va1 = *(const short8*)(h + (size_t)ra1 * D + i * 8);     \
    short8 vb0 = *(const short8*)(h + (size_t)rb0 * D + i * 8);     \
    short8 vb1 = *(const short8*)(h + (size_t)rb1 * D + i * 8);     \
    _Pragma("unroll") for (int q = 0; q < 8; ++q) {                 \
      a0[q] += b2f(va0[q]) + b2f(va1[q]);                           \
      a1[q] += b2f(vb0[q]) + b2f(vb1[q]);                           \
    }                                                               \
  }

// ---------------- K3: fused aggregate + output GEMM (512 thr, 32 nodes) ---
// Block = 32 nodes = 16 pairs. Phase A: waves work-steal pairs from an LDS
// counter (waves start with pair w, then grab 8..15) -> imbalance shrinks to
// single-pair tail. Phase B: wave w -> row-tile (w&1), col-tiles 2*(w>>1)+u.
__global__ __launch_bounds__(512) void k_fused(
    const int* __restrict__ cnt, const unsigned short* __restrict__ bucket,
    const short* __restrict__ h, const short* __restrict__ xbf,
    const short* __restrict__ WnT, const short* __restrict__ WgThi,
    const short* __restrict__ WgTlo, const float* __restrict__ bn,
    const float* __restrict__ bg, float* __restrict__ out) {
  __shared__ float st[32][132];
  __shared__ short xsb[32][132];
  __shared__ int nxt;
  int w = threadIdx.x >> 6, l = threadIdx.x & 63;
  int g = l >> 4, i = l & 15;
  int base = blockIdx.x * 32;

  // coalesced stage of xbf tile: 32 rows x 128 bf16 = 8KB; all 512 threads
  {
    int row = threadIdx.x >> 4, ch = threadIdx.x & 15;
    *(short8*)&xsb[row][ch * 8] =
        *(const short8*)(xbf + (size_t)(base + row) * D + ch * 8);
  }
  if (threadIdx.x == 0) nxt = 8;
  __syncthreads();

  // ---- Phase A: work-stealing over 16 pairs ----
  int p = w;
  while (true) {
    int n0 = base + 2 * p, n1 = n0 + 1;
    int deg0 = cnt[n0]; deg0 = deg0 < CAP ? deg0 : CAP;
    int deg1 = cnt[n1]; deg1 = deg1 < CAP ? deg1 : CAP;
    int dmax = deg0 > deg1 ? deg0 : deg1;
    int bc0 = bucket[(size_t)n0 * CAP + l];
    int bc1 = bucket[(size_t)n1 * CAP + l];
    float a0[8], a1[8];
#pragma unroll
    for (int q = 0; q < 8; ++q) { a0[q] = 0.f; a1[q] = 0.f; }

    int c00 = __shfl(bc0, g), c01 = __shfl(bc0, 4 + g);
    int c02 = __shfl(bc0, 8 + g), c03 = __shfl(bc0, 12 + g);
    int c10 = __shfl(bc1, g), c11 = __shfl(bc1, 4 + g);
    int c12 = __shfl(bc1, 8 + g), c13 = __shfl(bc1, 12 + g);
    PSTEP(0, c00, c01, c10, c11);
    if (dmax > 8) PSTEP(2, c02, c03, c12, c13);
    if (dmax > 16) {
      int c04 = __shfl(bc0, 16 + g), c05 = __shfl(bc0, 20 + g);
      int c14 = __shfl(bc1, 16 + g), c15 = __shfl(bc1, 20 + g);
      PSTEP(4, c04, c05, c14, c15);
    }
    if (dmax > 24) {
      int c06 = __shfl(bc0, 24 + g), c07 = __shfl(bc0, 28 + g);
      int c16_ = __shfl(bc1, 24 + g), c17 = __shfl(bc1, 28 + g);
      PSTEP(6, c06, c07, c16_, c17);
    }
    if (dmax > 32) {  // rare: P ~ 1e-4
      for (int j = 32; j < dmax; j += 8) {
        int s0 = j + g, s1 = j + 4 + g;
        int d00 = __shfl(bc0, s0 & 63), d01 = __shfl(bc0, s1 & 63);
        int d10 = __shfl(bc1, s0 & 63), d11 = __shfl(bc1, s1 & 63);
        int ra0 = s0 < deg0 ? d00 : NN;
        int ra1 = s1 < deg0 ? d01 : NN;
        int rb0 = s0 < deg1 ? d10 : NN;
        int rb1 = s1 < deg1 ? d11 : NN;
        short8 va0 = *(const short8*)(h + (size_t)ra0 * D + i * 8);
        short8 va1 = *(const short8*)(h + (size_t)ra1 * D + i * 8);
        short8 vb0 = *(const short8*)(h + (size_t)rb0 * D + i * 8);
        short8 vb1 = *(const short8*)(h + (size_t)rb1 * D + i * 8);
#pragma unroll
        for (int q = 0; q < 8; ++q) {
          a0[q] += b2f(va0[q]) + b2f(va1[q]);
          a1[q] += b2f(vb0[q]) + b2f(vb1[q]);
        }
      }
    }
#pragma unroll
    for (int q = 0; q < 8; ++q) {
      a0[q] += __shfl_xor(a0[q], 16);
      a0[q] += __shfl_xor(a0[q], 32);
      a1[q] += __shfl_xor(a1[q], 16);
      a1[q] += __shfl_xor(a1[q], 32);
    }
    if (g == 0) {
      f32x4 lo = {a0[0], a0[1], a0[2], a0[3]};
      f32x4 hi = {a0[4], a0[5], a0[6], a0[7]};
      *(f32x4*)&st[2 * p][i * 8] = lo;
      *(f32x4*)&st[2 * p][i * 8 + 4] = hi;
    } else if (g == 1) {
      f32x4 lo = {a1[0], a1[1], a1[2], a1[3]};
      f32x4 hi = {a1[4], a1[5], a1[6], a1[7]};
      *(f32x4*)&st[2 * p + 1][i * 8] = lo;
      *(f32x4*)&st[2 * p + 1][i * 8 + 4] = hi;
    }
    int np;
    if (l == 0) np = atomicAdd(&nxt, 1);
    np = __shfl(np, 0);
    if (np >= 16) break;
    p = np;
  }
  __syncthreads();

  // ---- Phase B: wave w -> row-tile rt=w&1, col-tiles ct=2*(w>>1)+u ----
  int rt = w & 1, ci = w >> 1;
  int rl = rt * 16 + i;  // local row for frags
  short8 axf[4], sh[4], sl[4];
#pragma unroll
  for (int kt = 0; kt < 4; ++kt) {
    axf[kt] = *(const short8*)&xsb[rl][kt * 32 + g * 8];
    const float* pp = &st[rl][kt * 32 + g * 8];
    f32x4 v0 = *(const f32x4*)pp;
    f32x4 v1 = *(const f32x4*)(pp + 4);
    short8 th, tl;
#pragma unroll
    for (int jq = 0; jq < 4; ++jq) {
      short hh = f2b(v0[jq]);
      th[jq] = hh;
      tl[jq] = f2b(v0[jq] - b2f(hh));
    }
#pragma unroll
    for (int jq = 0; jq < 4; ++jq) {
      short hh = f2b(v1[jq]);
      th[4 + jq] = hh;
      tl[4 + jq] = f2b(v1[jq] - b2f(hh));
    }
    sh[kt] = th;
    sl[kt] = tl;
  }

#pragma unroll
  for (int u = 0; u < 2; ++u) {
    int ct = ci * 2 + u;
    int cc = ct * 16 + i;
    f32x4 c = {0.f, 0.f, 0.f, 0.f};
#pragma unroll
    for (int kt = 0; kt < 4; ++kt) {
      short8 bwn = *(const short8*)(WnT + (size_t)cc * D + kt * 32 + g * 8);
      short8 bh = *(const short8*)(WgThi + (size_t)cc * D + kt * 32 + g * 8);
      short8 bl = *(const short8*)(WgTlo + (size_t)cc * D + kt * 32 + g * 8);
      c = __builtin_amdgcn_mfma_f32_16x16x32_bf16(axf[kt], bwn, c, 0, 0, 0);
      c = __builtin_amdgcn_mfma_f32_16x16x32_bf16(sh[kt], bh, c, 0, 0, 0);
      c = __builtin_amdgcn_mfma_f32_16x16x32_bf16(sl[kt], bh, c, 0, 0, 0);
      c = __builtin_amdgcn_mfma_f32_16x16x32_bf16(sh[kt], bl, c, 0, 0, 0);
    }
    float bias = bn[cc] + bg[cc];
#pragma unroll
    for (int r = 0; r < 4; ++r) {
      int rr = base + rt * 16 + g * 4 + r;
      out[(size_t)rr * D + cc] = tanhf(c[r] + bias);
    }
  }
}

extern "C" void kernel_launch(void* const* d_in, const int* in_sizes, int n_in,
                              void* d_out, int out_size, void* d_ws,
                              size_t ws_size, hipStream_t stream) {
  const float* x = (const float*)d_in[0];
  const int* ei = (const int*)d_in[1];
  const float* Wn_w = (const float*)d_in[2];
  const float* Wn_b = (const float*)d_in[3];
  const float* Wg_w = (const float*)d_in[4];
  const float* Wg_b = (const float*)d_in[5];
  const float* Wa_w = (const float*)d_in[6];
  const float* Wa_b = (const float*)d_in[7];

  char* ws = (char*)d_ws;
  short* WaT = (short*)(ws + 0);
  short* WnT = (short*)(ws + 32 * 1024);
  short* WgThi = (short*)(ws + 64 * 1024);
  short* WgTlo = (short*)(ws + 96 * 1024);
  int* cnt = (int*)(ws + 128 * 1024);  // 160 KB
  size_t off = 512 * 1024;
  short* h = (short*)(ws + off);  // (NN+1)*D*2 = 10.24 MB (+dummy row)
  off += (size_t)(NN + 1) * D * 2;
  short* xbf = (short*)(ws + off);  // 10.24 MB
  off += (size_t)NN * D * 2;
  unsigned short* bucket = (unsigned short*)(ws + off);  // 5.12 MB
  float* out = (float*)d_out;

  k_prep<<<64, 256, 0, stream>>>(Wn_w, Wg_w, Wa_w, WnT, WgThi, WgTlo, WaT,
                                 cnt, h);
  k_fill<<<(NE + 255) / 256, 256, 0, stream>>>(ei, cnt, bucket);
  k_node<<<NN / 16, 256, 0, stream>>>(x, WaT, Wa_b, h, xbf);
  k_fused<<<NN / 32, 512, 0, stream>>>(cnt, bucket, h, xbf, WnT, WgThi,
                                       WgTlo, Wn_b, Wg_b, out);
}

// Round 14
// 113.116 us; speedup vs baseline: 1.1284x; 1.0683x over previous
//
#include <hip/hip_runtime.h>

#define NN 40000
#define NE 640000
#define D 128
#define CAP 64  // bucket capacity; P(Poisson(16) >= 64) ~ 3e-22

typedef __attribute__((ext_vector_type(8))) short short8;
typedef __attribute__((ext_vector_type(4))) float f32x4;
typedef __attribute__((ext_vector_type(4))) int i32x4;

__device__ __forceinline__ short f2b(float v) {
  unsigned int u = __builtin_bit_cast(unsigned int, v);
  u = (u + 0x7fffu + ((u >> 16) & 1u)) >> 16;
  return (short)u;
}
__device__ __forceinline__ float b2f(short s) {
  unsigned int u = ((unsigned int)(unsigned short)s) << 16;
  return __builtin_bit_cast(float, u);
}

// ---------------- K0: weights (bf16 transpose + Wg hi/lo split), zero cnt,
// zero dummy h-row (index NN) used for branchless gather padding -----------
__global__ __launch_bounds__(256) void k_prep(
    const float* __restrict__ Wn, const float* __restrict__ Wg,
    const float* __restrict__ Wa, short* __restrict__ WnT,
    short* __restrict__ WgThi, short* __restrict__ WgTlo,
    short* __restrict__ WaT, int* __restrict__ cnt, short* __restrict__ h) {
  int i = blockIdx.x * 256 + threadIdx.x;  // 0..16383
  int k = i >> 7, c = i & 127;
  WnT[c * D + k] = f2b(Wn[k * D + c]);
  WaT[c * D + k] = f2b(Wa[k * D + c]);
  float v = Wg[k * D + c];
  short hi = f2b(v);
  WgThi[c * D + k] = hi;
  WgTlo[c * D + k] = f2b(v - b2f(hi));
  if (i < 10000) {  // zero cnt: 40000 ints = 10000 int4
    i32x4 z = {0, 0, 0, 0};
    *(i32x4*)(cnt + i * 4) = z;
  }
  if (i < 16) {  // zero dummy row h[NN]
    short8 z = {0, 0, 0, 0, 0, 0, 0, 0};
    *(short8*)(h + (size_t)NN * D + i * 8) = z;
  }
}

// ---------------- K1: edge bucket fill (u16 cols) ----------------
__global__ __launch_bounds__(256) void k_fill(
    const int* __restrict__ ei, int* __restrict__ cnt,
    unsigned short* __restrict__ bucket) {
  int e = blockIdx.x * 256 + threadIdx.x;
  if (e >= NE) return;
  int r = ei[e];       // destination row
  int c = ei[NE + e];  // source col
  int slot = atomicAdd(&cnt[r], 1);
  if (slot < CAP) bucket[(size_t)r * CAP + slot] = (unsigned short)c;
}

// ---------------- K2: node transform (16 rows/block, LDS-staged x) --------
// A-frag: lane l holds row (l&15), k = kt*32 + (l>>4)*8 + j
// B-frag: lane l holds col (l&15), same k slots -> permutation-safe.
// C/D: col = lane&15, row = (lane>>4)*4 + reg
__global__ __launch_bounds__(256) void k_node(
    const float* __restrict__ x, const short* __restrict__ WaT,
    const float* __restrict__ ba, short* __restrict__ h_out,
    short* __restrict__ xbf_out) {
  __shared__ float xs[16][132];    // x tile (staged coalesced)
  __shared__ float al_s[16][132];  // alpha tile
  int r0 = blockIdx.x * 16;
  int t = threadIdx.x;
  int w = t >> 6, l = t & 63;
  int g = l >> 4, c16 = l & 15;

#pragma unroll
  for (int p = 0; p < 2; ++p) {
    int idx = t + p * 256;  // 0..511
    int row = idx >> 5, cv = idx & 31;
    f32x4 v = *(const f32x4*)(x + (size_t)(r0 + row) * D + cv * 4);
    *(f32x4*)&xs[row][cv * 4] = v;
  }
  __syncthreads();

  short8 a[4];
#pragma unroll
  for (int kt = 0; kt < 4; ++kt) {
    f32x4 v0 = *(const f32x4*)&xs[c16][kt * 32 + g * 8];
    f32x4 v1 = *(const f32x4*)&xs[c16][kt * 32 + g * 8 + 4];
    short8 tt;
    tt[0] = f2b(v0[0]); tt[1] = f2b(v0[1]); tt[2] = f2b(v0[2]); tt[3] = f2b(v0[3]);
    tt[4] = f2b(v1[0]); tt[5] = f2b(v1[1]); tt[6] = f2b(v1[2]); tt[7] = f2b(v1[3]);
    a[kt] = tt;
    *(short8*)(xbf_out + (size_t)(r0 + c16) * D + kt * 32 + g * 8) = tt;
  }

#pragma unroll
  for (int u = 0; u < 2; ++u) {
    int ct = w * 2 + u;
    int cc = ct * 16 + c16;
    f32x4 c = {0.f, 0.f, 0.f, 0.f};
#pragma unroll
    for (int kt = 0; kt < 4; ++kt) {
      short8 b = *(const short8*)(WaT + (size_t)cc * D + kt * 32 + g * 8);
      c = __builtin_amdgcn_mfma_f32_16x16x32_bf16(a[kt], b, c, 0, 0, 0);
    }
    float bav = ba[cc];
#pragma unroll
    for (int r = 0; r < 4; ++r) {
      float tv = c[r] + bav;
      al_s[g * 4 + r][cc] = 1.0f / (1.0f + __expf(-tv));
    }
  }
  __syncthreads();

  // wave w handles channel chunk kt=w: h = x_f32 * alpha (bf16)
  short8 hh;
#pragma unroll
  for (int q = 0; q < 8; ++q) {
    float av = al_s[c16][w * 32 + g * 8 + q];
    float xv = xs[c16][w * 32 + g * 8 + q];
    hh[q] = f2b(xv * av);
  }
  *(short8*)(h_out + (size_t)(r0 + c16) * D + w * 32 + g * 8) = hh;
}

// 4 slots (S0+g, S0+4+g, S0+8+g, S0+12+g) -> 4 independent 16B gathers,
// register indices, branchless dummy-row clamp.
#define SSTEP(S0, CA, CB, CC, CD)                                   \
  {                                                                 \
    int q0 = (S0) + g < deg ? (CA) : NN;                            \
    int q1 = (S0) + 4 + g < deg ? (CB) : NN;                        \
    int q2 = (S0) + 8 + g < deg ? (CC) : NN;                        \
    int q3 = (S0) + 12 + g < deg ? (CD) : NN;                       \
    short8 v0 = *(const short8*)(h + (size_t)q0 * D + i * 8);       \
    short8 v1 = *(const short8*)(h + (size_t)q1 * D + i * 8);       \
    short8 v2 = *(const short8*)(h + (size_t)q2 * D + i * 8);       \
    short8 v3 = *(const short8*)(h + (size_t)q3 * D + i * 8);       \
    _Pragma("unroll") for (int q = 0; q < 8; ++q) {                 \
      acc[q] += b2f(v0[q]) + b2f(v1[q]);                            \
      acc[q] += b2f(v2[q]) + b2f(v3[q]);                            \
    }                                                               \
  }

// ---------------- K3: gather-aggregate (1 node/wave), emit split bf16 -----
// Group g handles slots {g,4+g,8+g,12+g,...}; chunk i=l&15 = channels
// [8i,8i+8). After shfl_xor reduce, g==0 lanes pack s as (hi<<16)|lo bf16
// pairs into u32 ssplit (same bytes as f32, but k_final needs no split).
__global__ __launch_bounds__(256) void k_aggr(
    const int* __restrict__ cnt, const unsigned short* __restrict__ bucket,
    const short* __restrict__ h, unsigned int* __restrict__ ssplit) {
  int l = threadIdx.x & 63;
  int n = blockIdx.x * 4 + (threadIdx.x >> 6);
  int g = l >> 4, i = l & 15;
  int deg = cnt[n];
  deg = deg < CAP ? deg : CAP;
  int bc = bucket[(size_t)n * CAP + l];
  float acc[8];
#pragma unroll
  for (int q = 0; q < 8; ++q) acc[q] = 0.f;

  int c0 = __shfl(bc, g), c1 = __shfl(bc, 4 + g);
  int c2 = __shfl(bc, 8 + g), c3 = __shfl(bc, 12 + g);
  SSTEP(0, c0, c1, c2, c3);
  if (deg > 16) {
    int c4 = __shfl(bc, 16 + g), c5 = __shfl(bc, 20 + g);
    int c6 = __shfl(bc, 24 + g), c7 = __shfl(bc, 28 + g);
    SSTEP(16, c4, c5, c6, c7);
  }
  if (deg > 32) {  // rare: P ~ 1.6e-4
    for (int j = 32; j < deg; j += 16) {
      int d0 = __shfl(bc, (j + g) & 63), d1 = __shfl(bc, (j + 4 + g) & 63);
      int d2 = __shfl(bc, (j + 8 + g) & 63), d3 = __shfl(bc, (j + 12 + g) & 63);
      SSTEP(j, d0, d1, d2, d3);
    }
  }

#pragma unroll
  for (int q = 0; q < 8; ++q) {
    acc[q] += __shfl_xor(acc[q], 16);
    acc[q] += __shfl_xor(acc[q], 32);
  }
  if (g == 0) {
    unsigned int u[8];
#pragma unroll
    for (int q = 0; q < 8; ++q) {
      short hi = f2b(acc[q]);
      short lo = f2b(acc[q] - b2f(hi));
      u[q] = ((unsigned int)(unsigned short)hi << 16) | (unsigned short)lo;
    }
    *(i32x4*)(ssplit + (size_t)n * D + i * 8) = *(i32x4*)&u[0];
    *(i32x4*)(ssplit + (size_t)n * D + i * 8 + 4) = *(i32x4*)&u[4];
  }
}

// ---------------- K4: out = tanh(xbf@Wn + s@Wg(split) + bn + bg) ----------
// 512 thr / 8 waves; wave w owns col-tile ct=w. All inputs bf16 (xbf from
// k_node, ssplit packed hi|lo from k_aggr) -> no float->bf16 VALU chains.
// Two independent MFMA chains (Wn-path, Wg-path) for ILP.
__global__ __launch_bounds__(512) void k_final(
    const short* __restrict__ xbf, const unsigned int* __restrict__ ssplit,
    const short* __restrict__ WnT, const short* __restrict__ WgThi,
    const short* __restrict__ WgTlo, const float* __restrict__ bn,
    const float* __restrict__ bg, float* __restrict__ out) {
  __shared__ unsigned int xsu[16][68];   // xbf tile as u32 (2 ch/word)
  __shared__ unsigned int ssu[16][132];  // ssplit tile (1 ch/word)
  int r0 = blockIdx.x * 16;
  int t = threadIdx.x;
  int w = t >> 6, l = t & 63;
  int g = l >> 4, c16 = l & 15;

  {
    int row = t >> 5, ch = t & 31;  // 512 chunks of ssplit tile
    *(i32x4*)&ssu[row][ch * 4] =
        *(const i32x4*)(ssplit + (size_t)(r0 + row) * D + ch * 4);
    if (t < 256) {  // 256 chunks of xbf tile
      int row2 = t >> 4, ch2 = t & 15;
      *(i32x4*)&xsu[row2][ch2 * 4] =
          *(const i32x4*)(xbf + (size_t)(r0 + row2) * D + ch2 * 8);
    }
  }
  __syncthreads();

  int cc = w * 16 + c16;
  f32x4 cn = {0.f, 0.f, 0.f, 0.f};
  f32x4 cg = {0.f, 0.f, 0.f, 0.f};
#pragma unroll
  for (int kt = 0; kt < 4; ++kt) {
    short8 axf =
        __builtin_bit_cast(short8, *(const i32x4*)&xsu[c16][kt * 16 + g * 4]);
    i32x4 u0 = *(const i32x4*)&ssu[c16][kt * 32 + g * 8];
    i32x4 u1 = *(const i32x4*)&ssu[c16][kt * 32 + g * 8 + 4];
    short8 shf, slf;
#pragma unroll
    for (int q = 0; q < 4; ++q) {
      unsigned int a = (unsigned int)u0[q], b = (unsigned int)u1[q];
      shf[q] = (short)(a >> 16);
      slf[q] = (short)(a & 0xffffu);
      shf[4 + q] = (short)(b >> 16);
      slf[4 + q] = (short)(b & 0xffffu);
    }
    short8 bwn = *(const short8*)(WnT + (size_t)cc * D + kt * 32 + g * 8);
    short8 bh = *(const short8*)(WgThi + (size_t)cc * D + kt * 32 + g * 8);
    short8 bl = *(const short8*)(WgTlo + (size_t)cc * D + kt * 32 + g * 8);
    cn = __builtin_amdgcn_mfma_f32_16x16x32_bf16(axf, bwn, cn, 0, 0, 0);
    cg = __builtin_amdgcn_mfma_f32_16x16x32_bf16(shf, bh, cg, 0, 0, 0);
    cg = __builtin_amdgcn_mfma_f32_16x16x32_bf16(slf, bh, cg, 0, 0, 0);
    cg = __builtin_amdgcn_mfma_f32_16x16x32_bf16(shf, bl, cg, 0, 0, 0);
  }
  float bias = bn[cc] + bg[cc];
#pragma unroll
  for (int r = 0; r < 4; ++r) {
    int rr = r0 + g * 4 + r;
    out[(size_t)rr * D + cc] = tanhf(cn[r] + cg[r] + bias);
  }
}

extern "C" void kernel_launch(void* const* d_in, const int* in_sizes, int n_in,
                              void* d_out, int out_size, void* d_ws,
                              size_t ws_size, hipStream_t stream) {
  const float* x = (const float*)d_in[0];
  const int* ei = (const int*)d_in[1];
  const float* Wn_w = (const float*)d_in[2];
  const float* Wn_b = (const float*)d_in[3];
  const float* Wg_w = (const float*)d_in[4];
  const float* Wg_b = (const float*)d_in[5];
  const float* Wa_w = (const float*)d_in[6];
  const float* Wa_b = (const float*)d_in[7];

  char* ws = (char*)d_ws;
  short* WaT = (short*)(ws + 0);
  short* WnT = (short*)(ws + 32 * 1024);
  short* WgThi = (short*)(ws + 64 * 1024);
  short* WgTlo = (short*)(ws + 96 * 1024);
  int* cnt = (int*)(ws + 128 * 1024);  // 160 KB
  size_t off = 512 * 1024;
  short* h = (short*)(ws + off);  // (NN+1)*D*2 = 10.24 MB (+dummy row)
  off += (size_t)(NN + 1) * D * 2;
  short* xbf = (short*)(ws + off);  // 10.24 MB
  off += (size_t)NN * D * 2;
  unsigned short* bucket = (unsigned short*)(ws + off);  // 5.12 MB
  off += (size_t)NN * CAP * 2;
  unsigned int* ssplit = (unsigned int*)(ws + off);  // 20.48 MB
  float* out = (float*)d_out;

  k_prep<<<64, 256, 0, stream>>>(Wn_w, Wg_w, Wa_w, WnT, WgThi, WgTlo, WaT,
                                 cnt, h);
  k_fill<<<(NE + 255) / 256, 256, 0, stream>>>(ei, cnt, bucket);
  k_node<<<NN / 16, 256, 0, stream>>>(x, WaT, Wa_b, h, xbf);
  k_aggr<<<NN / 4, 256, 0, stream>>>(cnt, bucket, h, ssplit);
  k_final<<<NN / 16, 512, 0, stream>>>(xbf, ssplit, WnT, WgThi, WgTlo, Wn_b,
                                       Wg_b, out);
}